// Round 6
// baseline (1899.686 us; speedup 1.0000x reference)
//
#include <hip/hip_runtime.h>

// DeepSet: N=1M nodes, G=10k graphs (sorted segment ids), HIDDEN=50, 2 layers.
// v5 (resubmit; prior run died to container infra, not the kernel):
// occupancy uncapped on k_layer (launch_bounds 3 -> 8 waves/EU; VGPR=56 fits 8
// waves), float4 k_bnapply, 4-wave-parallel k_gt1.
//   k_pre      : W^T MFMA fragments (f16 hi/lo, uint4-interleaved) + padded biases
//                + start[] binary search + psum/psq zeroing
//   k_ginit0   : per-graph xy mean (wave reduce) + tg = glob@Ws1[0][:50]+bs1[0]
//   k_layer<L> : register-resident MFMA matvec chain (v_mfma_f32_16x16x16_f16,
//                fp32 emu: xh@Wh + xl@Wh + xh@Wl); epilogue computes BN sum/sumsq
//                from registers (shfl_xor reduce + 64-slot atomics).
//   k_finalize : a,c from psum/psq; re-zeros psum/psq for next layer
//   k_gt1      : per-graph sum of x1 -> BN1 affine -> tg for layer 2
//   k_bnapply  : out = out*a2 + c2 (float4 grid-stride)

#define GN 10000
#define H 50
#define EPSV 1e-5f

typedef __attribute__((ext_vector_type(4))) float f32x4;
typedef __attribute__((ext_vector_type(2))) __fp16 fp16x2;
typedef __attribute__((ext_vector_type(4))) _Float16 half4_t;

union H4 { half4_t h; uint2 u; };

static __device__ __forceinline__ f32x4 mfma16(half4_t a, half4_t b, f32x4 c){
#if __has_builtin(__builtin_amdgcn_mfma_f32_16x16x16f16)
  return __builtin_amdgcn_mfma_f32_16x16x16f16(a, b, c, 0, 0, 0);
#else
  asm volatile("v_mfma_f32_16x16x16_f16 %0, %1, %2, %0" : "+v"(c) : "v"(a), "v"(b));
  return c;
#endif
}

// split fp32x4 into f16 hi plane + f16 residual plane
static __device__ __forceinline__ void split4(f32x4 v, H4& hh, H4& hl){
  fp16x2 a = __builtin_amdgcn_cvt_pkrtz(v[0], v[1]);
  fp16x2 b = __builtin_amdgcn_cvt_pkrtz(v[2], v[3]);
  hh.u.x = __builtin_bit_cast(unsigned int, a);
  hh.u.y = __builtin_bit_cast(unsigned int, b);
  float r0 = v[0] - (float)a[0];
  float r1 = v[1] - (float)a[1];
  float r2 = v[2] - (float)b[0];
  float r3 = v[3] - (float)b[1];
  fp16x2 c = __builtin_amdgcn_cvt_pkrtz(r0, r1);
  fp16x2 d = __builtin_amdgcn_cvt_pkrtz(r2, r3);
  hl.u.x = __builtin_bit_cast(unsigned int, c);
  hl.u.y = __builtin_bit_cast(unsigned int, d);
}

// ---- fused prepass: W fragments + padded biases + start[] + psum/psq zero ----
// frag uint4 layout: t = ((L*5+m)*4 + Mt)*4*64 + ks*64 + lane;
//   .xy = hi plane (4 f16), .zw = lo plane. A layout (16x16x16):
//   row j_out = Mt*16 + (lane&15); k_in = ks*16 + (lane>>4)*4 + e.
__global__ void k_pre(const float* __restrict__ Ws1, const float* __restrict__ Ws,
                      const float* __restrict__ bs, const int* __restrict__ sid, int N,
                      uint4* __restrict__ frag, float* __restrict__ pbias,
                      int* __restrict__ start, float* __restrict__ pzero){
  int t = blockIdx.x*blockDim.x + threadIdx.x;
  if (t < 10240){
    int lane = t & 63;
    int ks   = (t>>6) & 3;
    int Mt   = (t>>8) & 3;
    int rest = t >> 10;                 // 0..9 = L*5 + m
    int m = rest % 5, L = rest / 5;
    const float* W = (m == 0) ? (Ws1 + L*100*H + H*H) : (Ws + (L*4 + (m-1))*H*H);
    int jo = Mt*16 + (lane & 15);
    int kb = ks*16 + ((lane>>4)<<2);
    f32x4 v;
    #pragma unroll
    for (int e = 0; e < 4; ++e){
      int k = kb + e;
      v[e] = (k < H && jo < H) ? W[k*H + jo] : 0.f;   // zero-pad kills 50->64 pad
    }
    H4 hh, hl;
    split4(v, hh, hl);
    frag[t] = make_uint4(hh.u.x, hh.u.y, hl.u.x, hl.u.y);
  } else if (t < 10752){
    int i = t - 10240;                  // (L*4+mi)*64 + j, 512 entries
    int j = i & 63;
    int row = i >> 6;
    pbias[i] = (j < H) ? bs[row*H + j] : 0.f;
  } else if (t < 20753){
    int g = t - 10752;                  // 0..10000
    int lo = 0, hi = N;
    while (lo < hi){ int mid = (lo+hi)>>1; if (sid[mid] < g) lo = mid+1; else hi = mid; }
    start[g] = lo;
  } else if (t >= 20800 && t < 27200){
    pzero[t - 20800] = 0.f;             // psum+psq contiguous, 6400 floats
  }
}

// ---- per-graph: xy mean + tg for layer 0 ----
__global__ void k_ginit0(const float2* __restrict__ xy, const int* __restrict__ start,
                         const float* __restrict__ w_init, const float* __restrict__ b_init,
                         const float* __restrict__ Ws1, const float* __restrict__ bs1,
                         float* __restrict__ tg){
  __shared__ float glob[H];
  int g = blockIdx.x; int l = threadIdx.x;     // 64 threads = 1 wave
  int s = start[g], e = start[g+1];
  float sx = 0.f, sy = 0.f;
  for (int n = s + l; n < e; n += 64){ float2 v = xy[n]; sx += v.x; sy += v.y; }
  #pragma unroll
  for (int off = 32; off > 0; off >>= 1){ sx += __shfl_xor(sx, off); sy += __shfl_xor(sy, off); }
  int cnt = e - s; if (cnt < 1) cnt = 1;
  float inv = 1.f/(float)cnt;
  if (l < H) glob[l] = b_init[l] + sx*inv*w_init[l] + sy*inv*w_init[H+l];
  __syncthreads();
  if (l < H){
    float a = bs1[l];
    #pragma unroll 5
    for (int k = 0; k < H; ++k) a = fmaf(glob[k], Ws1[k*H + l], a);
    tg[(size_t)g*H + l] = a;
  }
}

template<int LAYER>
__global__ __launch_bounds__(256, 8)
void k_layer(const float2* __restrict__ xy, const int* __restrict__ sid,
             const float* __restrict__ tg, const uint4* __restrict__ frag,
             const float* __restrict__ pbias,
             const float* __restrict__ w_init, const float* __restrict__ b_init,
             const float* __restrict__ stats,
             float* __restrict__ psum, float* __restrict__ psq,
             float* __restrict__ xio, int N)
{
  const int tid = threadIdx.x;
  const int wv = tid >> 6, l = tid & 63, lg = l >> 4, ll = l & 15;
  const int base = blockIdx.x*128 + wv*32;     // 32 nodes per wave, 4 waves/block

  // ---- B-fragments for matvec 0: col n = node = Nt*16+ll, k = ks*16 + lg*4 + e ----
  H4 bh[2][4], bl[2][4];
  #pragma unroll
  for (int Nt = 0; Nt < 2; ++Nt){
    int node = base + Nt*16 + ll;
    int nc = node < N ? node : N-1;
    float xv[16];
    if (LAYER == 0){
      float2 p = xy[nc];
      #pragma unroll
      for (int ks = 0; ks < 4; ++ks)
        #pragma unroll
        for (int e = 0; e < 4; ++e){
          int k = ks*16 + lg*4 + e; int kc = k < H ? k : H-1;   // pad -> finite garbage, W-zeros kill it
          xv[ks*4+e] = b_init[kc] + p.x*w_init[kc] + p.y*w_init[H+kc];
        }
    } else {
      #pragma unroll
      for (int ks = 0; ks < 4; ++ks){
        int k0 = ks*16 + lg*4;
        size_t f0 = (size_t)nc*H + k0;
        size_t fm = (size_t)N*H - 2;
        float2 u0 = *(const float2*)(xio + (f0     < fm ? f0     : fm));
        float2 u1 = *(const float2*)(xio + (f0 + 2 < fm ? f0 + 2 : fm));
        float vv[4] = {u0.x, u0.y, u1.x, u1.y};
        #pragma unroll
        for (int e = 0; e < 4; ++e){
          int kc = (k0+e) < H ? (k0+e) : H-1;
          xv[ks*4+e] = vv[e]*stats[kc] + stats[H+kc];          // BN1 affine on the way in
        }
      }
    }
    #pragma unroll
    for (int ks = 0; ks < 4; ++ks){
      f32x4 v; v[0]=xv[ks*4]; v[1]=xv[ks*4+1]; v[2]=xv[ks*4+2]; v[3]=xv[ks*4+3];
      split4(v, bh[Nt][ks], bl[Nt][ks]);
    }
  }

  // ---- acc init = tg[g] (per-graph glob part + bs1, fp32-exact) ----
  // D layout: col n = node = Nt*16+ll, row j = Mt*16 + lg*4 + r
  f32x4 acc[4][2];
  {
    int n0 = base + ll;       n0 = n0 < N ? n0 : N-1;
    int n1 = base + 16 + ll;  n1 = n1 < N ? n1 : N-1;
    const float* t0 = tg + (size_t)sid[n0]*H;
    const float* t1 = tg + (size_t)sid[n1]*H;
    #pragma unroll
    for (int Mt = 0; Mt < 4; ++Mt)
      #pragma unroll
      for (int r = 0; r < 4; ++r){
        int j = Mt*16 + lg*4 + r; int jc = j < H ? j : H-1;
        acc[Mt][0][r] = t0[jc];
        acc[Mt][1][r] = t1[jc];
      }
  }

  // ---- 5 chained matvecs; output regs become next B-frags (no LDS, no shuffles) ----
  #pragma unroll
  for (int m = 0; m < 5; ++m){
    const uint4* fp = frag + (LAYER*5 + m)*1024;
    #pragma unroll
    for (int Mt = 0; Mt < 4; ++Mt){
      H4 ah[4], al[4];
      #pragma unroll
      for (int ks = 0; ks < 4; ++ks){
        uint4 w = fp[(Mt*4 + ks)*64 + l];          // one dwordx4: hi + lo planes
        ah[ks].u = make_uint2(w.x, w.y);
        al[ks].u = make_uint2(w.z, w.w);
      }
      #pragma unroll
      for (int Nt = 0; Nt < 2; ++Nt){
        f32x4 c = acc[Mt][Nt];
        #pragma unroll
        for (int ks = 0; ks < 4; ++ks) c = mfma16(ah[ks].h, bh[Nt][ks].h, c);  // Wh*xh
        #pragma unroll
        for (int ks = 0; ks < 4; ++ks) c = mfma16(al[ks].h, bh[Nt][ks].h, c);  // Wl*xh
        #pragma unroll
        for (int ks = 0; ks < 4; ++ks) c = mfma16(ah[ks].h, bl[Nt][ks].h, c);  // Wh*xl
        acc[Mt][Nt] = c;
      }
    }
    if (m < 4){
      // relu -> split -> B-frags in place (kstep of next matvec = Mt of this output)
      #pragma unroll
      for (int Mt = 0; Mt < 4; ++Mt){
        const f32x4 bv = *(const f32x4*)(pbias + (LAYER*4 + m)*64 + Mt*16 + (lg<<2));
        #pragma unroll
        for (int Nt = 0; Nt < 2; ++Nt){
          f32x4 v = acc[Mt][Nt];
          v[0]=fmaxf(v[0],0.f); v[1]=fmaxf(v[1],0.f); v[2]=fmaxf(v[2],0.f); v[3]=fmaxf(v[3],0.f);
          split4(v, bh[Nt][Mt], bl[Nt][Mt]);
          acc[Mt][Nt] = bv;                          // bias of next matvec
        }
      }
    }
  }

  // ---- store final matvec output (no relu), only j < 50 ----
  #pragma unroll
  for (int Nt = 0; Nt < 2; ++Nt){
    int node = base + Nt*16 + ll;
    if (node < N){
      float* row = xio + (size_t)node*H;
      #pragma unroll
      for (int Mt = 0; Mt < 3; ++Mt){
        int j0 = Mt*16 + (lg<<2);
        *(float2*)(row + j0)     = make_float2(acc[Mt][Nt][0], acc[Mt][Nt][1]);
        *(float2*)(row + j0 + 2) = make_float2(acc[Mt][Nt][2], acc[Mt][Nt][3]);
      }
      if (lg == 0)
        *(float2*)(row + 48) = make_float2(acc[3][Nt][0], acc[3][Nt][1]);
    }
  }

  // ---- fused BN-stats epilogue: psum/psq from registers ----
  // per (Mt,r): j fixed per lane-group; reduce over 16 ll-lanes (2 nodes each)
  {
    int slot = (int)(blockIdx.x & 63);
    #pragma unroll
    for (int Mt = 0; Mt < 4; ++Mt)
      #pragma unroll
      for (int r = 0; r < 4; ++r){
        int j = Mt*16 + lg*4 + r;
        float s = 0.f, q = 0.f;
        #pragma unroll
        for (int Nt = 0; Nt < 2; ++Nt){
          int node = base + Nt*16 + ll;
          float v = (node < N && j < H) ? acc[Mt][Nt][r] : 0.f;
          s += v; q = fmaf(v, v, q);
        }
        #pragma unroll
        for (int off = 8; off > 0; off >>= 1){ s += __shfl_xor(s, off); q += __shfl_xor(q, off); }
        if (ll == 0 && j < H){
          atomicAdd(&psum[slot*H + j], s);
          atomicAdd(&psq [slot*H + j], q);
        }
      }
  }
}

__global__ void k_finalize(float* __restrict__ psum, float* __restrict__ psq,
                           const float* __restrict__ gamma, const float* __restrict__ beta,
                           int layer, float ninv, float* __restrict__ stats){
  int j = threadIdx.x;
  if (j >= H) return;
  float s = 0.f, q = 0.f;
  #pragma unroll 8
  for (int p = 0; p < 64; ++p){ s += psum[p*H + j]; q += psq[p*H + j]; }
  float mu  = s*ninv;
  float var = q*ninv - mu*mu;
  float a = rsqrtf(var + EPSV) * gamma[layer*H + j];
  float c = beta[layer*H + j] - mu*a;
  stats[layer*100 + j]     = a;
  stats[layer*100 + H + j] = c;
  // re-zero for next layer's atomics (each (p,j) read only by this thread)
  #pragma unroll 8
  for (int p = 0; p < 64; ++p){ psum[p*H + j] = 0.f; psq[p*H + j] = 0.f; }
}

// ---- per-graph: gsum of x1 (4-wave parallel) -> BN1 affine -> tg for layer 2 ----
__global__ void k_gt1(const float* __restrict__ x, const int* __restrict__ start,
                      const float* __restrict__ stats,
                      const float* __restrict__ Ws1, const float* __restrict__ bs1,
                      float* __restrict__ tg){
  __shared__ float part[4][H];
  __shared__ float glob[H];
  int g = blockIdx.x;
  int t = threadIdx.x;                 // 256 = 4 waves
  int w = t >> 6, j = t & 63;
  int s = start[g], e = start[g+1];
  if (j < H){
    float acc = 0.f;
    for (int n = s + w; n < e; n += 4) acc += x[(size_t)n*H + j];
    part[w][j] = acc;
  }
  __syncthreads();
  if (t < H){
    int cnt = e - s; if (cnt < 1) cnt = 1;
    float m = (part[0][t] + part[1][t] + part[2][t] + part[3][t]) / (float)cnt;
    glob[t] = m*stats[t] + stats[H+t];   // a1, c1
  }
  __syncthreads();
  if (t < H){
    const float* W = Ws1 + 100*H;        // Ws1[1] rows 0..49
    float a = bs1[H + t];
    #pragma unroll 5
    for (int k = 0; k < H; ++k) a = fmaf(glob[k], W[k*H + t], a);
    tg[(size_t)g*H + t] = a;
  }
}

// ---- BN2 apply, float4 grid-stride (N*H = 50M floats = 12.5M float4 exactly) ----
__global__ void k_bnapply(float4* __restrict__ x4, const float* __restrict__ stats, int n4){
  __shared__ float a[H], c[H];
  if (threadIdx.x < H){ a[threadIdx.x] = stats[100 + threadIdx.x]; c[threadIdx.x] = stats[150 + threadIdx.x]; }
  __syncthreads();
  int idx = blockIdx.x*blockDim.x + threadIdx.x;
  int stride = gridDim.x*blockDim.x;
  for (; idx < n4; idx += stride){
    float4 v = x4[idx];
    int j0 = (idx*4) % 50;
    int j1 = j0+1; if (j1 >= 50) j1 -= 50;
    int j2 = j0+2; if (j2 >= 50) j2 -= 50;
    int j3 = j0+3; if (j3 >= 50) j3 -= 50;
    v.x = v.x*a[j0] + c[j0];
    v.y = v.y*a[j1] + c[j1];
    v.z = v.z*a[j2] + c[j2];
    v.w = v.w*a[j3] + c[j3];
    x4[idx] = v;
  }
}

extern "C" void kernel_launch(void* const* d_in, const int* in_sizes, int n_in,
                              void* d_out, int out_size, void* d_ws, size_t ws_size,
                              hipStream_t stream) {
  const float2* xy     = (const float2*)d_in[0];
  const int*    sid    = (const int*)d_in[1];
  const float*  w_init = (const float*)d_in[3];
  const float*  b_init = (const float*)d_in[4];
  const float*  Ws1    = (const float*)d_in[5];
  const float*  bs1    = (const float*)d_in[6];
  const float*  Ws     = (const float*)d_in[7];
  const float*  bs     = (const float*)d_in[8];
  const float*  gamma  = (const float*)d_in[9];
  const float*  beta   = (const float*)d_in[10];
  float* out = (float*)d_out;
  int N = in_sizes[0] / 2;
  const int G = GN;

  char* ws = (char*)d_ws;
  int*   start = (int*)ws;                      // 40,004 B          [0 .. 40064)
  float* tg    = (float*)(ws + 40064);          // 50G floats (2 MB) [.. 2040064)
  float* psum  = (float*)(ws + 2040064);        // 64*50 floats      [.. 2052864)
  float* psq   = (float*)(ws + 2052864);        // 64*50 floats      [.. 2065664)
  float* stats = (float*)(ws + 2065664);        // 200 floats        [.. 2066464)
  uint4* frag  = (uint4*)(ws + 2066560);        // 163,840 B         [.. 2230400)
  float* pbias = (float*)(ws + 2230400);        // 2,048 B

  int nb = (N + 127)/128;
  int n4 = (N*H)/4;

  k_pre<<<107, 256, 0, stream>>>(Ws1, Ws, bs, sid, N, frag, pbias, start, psum);
  k_ginit0<<<G, 64, 0, stream>>>(xy, start, w_init, b_init, Ws1, bs1, tg);
  k_layer<0><<<nb, 256, 0, stream>>>(xy, sid, tg, frag, pbias, w_init, b_init, stats, psum, psq, out, N);
  k_finalize<<<1, 64, 0, stream>>>(psum, psq, gamma, beta, 0, 1.0f/(float)N, stats);
  k_gt1<<<G, 256, 0, stream>>>(out, start, stats, Ws1, bs1, tg);
  k_layer<1><<<nb, 256, 0, stream>>>(xy, sid, tg, frag, pbias, w_init, b_init, stats, psum, psq, out, N);
  k_finalize<<<1, 64, 0, stream>>>(psum, psq, gamma, beta, 1, 1.0f/(float)N, stats);
  k_bnapply<<<4096, 256, 0, stream>>>((float4*)out, stats, n4);
}

// Round 7
// 1090.649 us; speedup vs baseline: 1.7418x; 1.7418x over previous
//
#include <hip/hip_runtime.h>

// DeepSet: N=1M nodes, G=10k graphs (sorted segment ids), HIDDEN=50, 2 layers.
// v6: v5 with launch_bounds(256,6) on k_layer.
//   (256,8) spilled: 64-reg budget -> 32 arch VGPR -> 3 GB scratch traffic/dispatch.
//   (256,6) = 85-reg budget fits the ~56-reg working set and doubles waves vs (256,3).
//   k_pre      : W^T MFMA fragments (f16 hi/lo, uint4-interleaved) + padded biases
//                + start[] binary search + psum/psq zeroing
//   k_ginit0   : per-graph xy mean (wave reduce) + tg = glob@Ws1[0][:50]+bs1[0]
//   k_layer<L> : register-resident MFMA matvec chain (v_mfma_f32_16x16x16_f16,
//                fp32 emu: xh@Wh + xl@Wh + xh@Wl); epilogue computes BN sum/sumsq
//                from registers (shfl_xor reduce + 64-slot atomics).
//   k_finalize : a,c from psum/psq; re-zeros psum/psq for next layer
//   k_gt1      : per-graph sum of x1 -> BN1 affine -> tg for layer 2
//   k_bnapply  : out = out*a2 + c2 (float4 grid-stride)

#define GN 10000
#define H 50
#define EPSV 1e-5f

typedef __attribute__((ext_vector_type(4))) float f32x4;
typedef __attribute__((ext_vector_type(2))) __fp16 fp16x2;
typedef __attribute__((ext_vector_type(4))) _Float16 half4_t;

union H4 { half4_t h; uint2 u; };

static __device__ __forceinline__ f32x4 mfma16(half4_t a, half4_t b, f32x4 c){
#if __has_builtin(__builtin_amdgcn_mfma_f32_16x16x16f16)
  return __builtin_amdgcn_mfma_f32_16x16x16f16(a, b, c, 0, 0, 0);
#else
  asm volatile("v_mfma_f32_16x16x16_f16 %0, %1, %2, %0" : "+v"(c) : "v"(a), "v"(b));
  return c;
#endif
}

// split fp32x4 into f16 hi plane + f16 residual plane
static __device__ __forceinline__ void split4(f32x4 v, H4& hh, H4& hl){
  fp16x2 a = __builtin_amdgcn_cvt_pkrtz(v[0], v[1]);
  fp16x2 b = __builtin_amdgcn_cvt_pkrtz(v[2], v[3]);
  hh.u.x = __builtin_bit_cast(unsigned int, a);
  hh.u.y = __builtin_bit_cast(unsigned int, b);
  float r0 = v[0] - (float)a[0];
  float r1 = v[1] - (float)a[1];
  float r2 = v[2] - (float)b[0];
  float r3 = v[3] - (float)b[1];
  fp16x2 c = __builtin_amdgcn_cvt_pkrtz(r0, r1);
  fp16x2 d = __builtin_amdgcn_cvt_pkrtz(r2, r3);
  hl.u.x = __builtin_bit_cast(unsigned int, c);
  hl.u.y = __builtin_bit_cast(unsigned int, d);
}

// ---- fused prepass: W fragments + padded biases + start[] + psum/psq zero ----
// frag uint4 layout: t = ((L*5+m)*4 + Mt)*4*64 + ks*64 + lane;
//   .xy = hi plane (4 f16), .zw = lo plane. A layout (16x16x16):
//   row j_out = Mt*16 + (lane&15); k_in = ks*16 + (lane>>4)*4 + e.
__global__ void k_pre(const float* __restrict__ Ws1, const float* __restrict__ Ws,
                      const float* __restrict__ bs, const int* __restrict__ sid, int N,
                      uint4* __restrict__ frag, float* __restrict__ pbias,
                      int* __restrict__ start, float* __restrict__ pzero){
  int t = blockIdx.x*blockDim.x + threadIdx.x;
  if (t < 10240){
    int lane = t & 63;
    int ks   = (t>>6) & 3;
    int Mt   = (t>>8) & 3;
    int rest = t >> 10;                 // 0..9 = L*5 + m
    int m = rest % 5, L = rest / 5;
    const float* W = (m == 0) ? (Ws1 + L*100*H + H*H) : (Ws + (L*4 + (m-1))*H*H);
    int jo = Mt*16 + (lane & 15);
    int kb = ks*16 + ((lane>>4)<<2);
    f32x4 v;
    #pragma unroll
    for (int e = 0; e < 4; ++e){
      int k = kb + e;
      v[e] = (k < H && jo < H) ? W[k*H + jo] : 0.f;   // zero-pad kills 50->64 pad
    }
    H4 hh, hl;
    split4(v, hh, hl);
    frag[t] = make_uint4(hh.u.x, hh.u.y, hl.u.x, hl.u.y);
  } else if (t < 10752){
    int i = t - 10240;                  // (L*4+mi)*64 + j, 512 entries
    int j = i & 63;
    int row = i >> 6;
    pbias[i] = (j < H) ? bs[row*H + j] : 0.f;
  } else if (t < 20753){
    int g = t - 10752;                  // 0..10000
    int lo = 0, hi = N;
    while (lo < hi){ int mid = (lo+hi)>>1; if (sid[mid] < g) lo = mid+1; else hi = mid; }
    start[g] = lo;
  } else if (t >= 20800 && t < 27200){
    pzero[t - 20800] = 0.f;             // psum+psq contiguous, 6400 floats
  }
}

// ---- per-graph: xy mean + tg for layer 0 ----
__global__ void k_ginit0(const float2* __restrict__ xy, const int* __restrict__ start,
                         const float* __restrict__ w_init, const float* __restrict__ b_init,
                         const float* __restrict__ Ws1, const float* __restrict__ bs1,
                         float* __restrict__ tg){
  __shared__ float glob[H];
  int g = blockIdx.x; int l = threadIdx.x;     // 64 threads = 1 wave
  int s = start[g], e = start[g+1];
  float sx = 0.f, sy = 0.f;
  for (int n = s + l; n < e; n += 64){ float2 v = xy[n]; sx += v.x; sy += v.y; }
  #pragma unroll
  for (int off = 32; off > 0; off >>= 1){ sx += __shfl_xor(sx, off); sy += __shfl_xor(sy, off); }
  int cnt = e - s; if (cnt < 1) cnt = 1;
  float inv = 1.f/(float)cnt;
  if (l < H) glob[l] = b_init[l] + sx*inv*w_init[l] + sy*inv*w_init[H+l];
  __syncthreads();
  if (l < H){
    float a = bs1[l];
    #pragma unroll 5
    for (int k = 0; k < H; ++k) a = fmaf(glob[k], Ws1[k*H + l], a);
    tg[(size_t)g*H + l] = a;
  }
}

template<int LAYER>
__global__ __launch_bounds__(256, 6)
void k_layer(const float2* __restrict__ xy, const int* __restrict__ sid,
             const float* __restrict__ tg, const uint4* __restrict__ frag,
             const float* __restrict__ pbias,
             const float* __restrict__ w_init, const float* __restrict__ b_init,
             const float* __restrict__ stats,
             float* __restrict__ psum, float* __restrict__ psq,
             float* __restrict__ xio, int N)
{
  const int tid = threadIdx.x;
  const int wv = tid >> 6, l = tid & 63, lg = l >> 4, ll = l & 15;
  const int base = blockIdx.x*128 + wv*32;     // 32 nodes per wave, 4 waves/block

  // ---- B-fragments for matvec 0: col n = node = Nt*16+ll, k = ks*16 + lg*4 + e ----
  H4 bh[2][4], bl[2][4];
  #pragma unroll
  for (int Nt = 0; Nt < 2; ++Nt){
    int node = base + Nt*16 + ll;
    int nc = node < N ? node : N-1;
    float xv[16];
    if (LAYER == 0){
      float2 p = xy[nc];
      #pragma unroll
      for (int ks = 0; ks < 4; ++ks)
        #pragma unroll
        for (int e = 0; e < 4; ++e){
          int k = ks*16 + lg*4 + e; int kc = k < H ? k : H-1;   // pad -> finite garbage, W-zeros kill it
          xv[ks*4+e] = b_init[kc] + p.x*w_init[kc] + p.y*w_init[H+kc];
        }
    } else {
      #pragma unroll
      for (int ks = 0; ks < 4; ++ks){
        int k0 = ks*16 + lg*4;
        size_t f0 = (size_t)nc*H + k0;
        size_t fm = (size_t)N*H - 2;
        float2 u0 = *(const float2*)(xio + (f0     < fm ? f0     : fm));
        float2 u1 = *(const float2*)(xio + (f0 + 2 < fm ? f0 + 2 : fm));
        float vv[4] = {u0.x, u0.y, u1.x, u1.y};
        #pragma unroll
        for (int e = 0; e < 4; ++e){
          int kc = (k0+e) < H ? (k0+e) : H-1;
          xv[ks*4+e] = vv[e]*stats[kc] + stats[H+kc];          // BN1 affine on the way in
        }
      }
    }
    #pragma unroll
    for (int ks = 0; ks < 4; ++ks){
      f32x4 v; v[0]=xv[ks*4]; v[1]=xv[ks*4+1]; v[2]=xv[ks*4+2]; v[3]=xv[ks*4+3];
      split4(v, bh[Nt][ks], bl[Nt][ks]);
    }
  }

  // ---- acc init = tg[g] (per-graph glob part + bs1, fp32-exact) ----
  // D layout: col n = node = Nt*16+ll, row j = Mt*16 + lg*4 + r
  f32x4 acc[4][2];
  {
    int n0 = base + ll;       n0 = n0 < N ? n0 : N-1;
    int n1 = base + 16 + ll;  n1 = n1 < N ? n1 : N-1;
    const float* t0 = tg + (size_t)sid[n0]*H;
    const float* t1 = tg + (size_t)sid[n1]*H;
    #pragma unroll
    for (int Mt = 0; Mt < 4; ++Mt)
      #pragma unroll
      for (int r = 0; r < 4; ++r){
        int j = Mt*16 + lg*4 + r; int jc = j < H ? j : H-1;
        acc[Mt][0][r] = t0[jc];
        acc[Mt][1][r] = t1[jc];
      }
  }

  // ---- 5 chained matvecs; output regs become next B-frags (no LDS, no shuffles) ----
  #pragma unroll
  for (int m = 0; m < 5; ++m){
    const uint4* fp = frag + (LAYER*5 + m)*1024;
    #pragma unroll
    for (int Mt = 0; Mt < 4; ++Mt){
      H4 ah[4], al[4];
      #pragma unroll
      for (int ks = 0; ks < 4; ++ks){
        uint4 w = fp[(Mt*4 + ks)*64 + l];          // one dwordx4: hi + lo planes
        ah[ks].u = make_uint2(w.x, w.y);
        al[ks].u = make_uint2(w.z, w.w);
      }
      #pragma unroll
      for (int Nt = 0; Nt < 2; ++Nt){
        f32x4 c = acc[Mt][Nt];
        #pragma unroll
        for (int ks = 0; ks < 4; ++ks) c = mfma16(ah[ks].h, bh[Nt][ks].h, c);  // Wh*xh
        #pragma unroll
        for (int ks = 0; ks < 4; ++ks) c = mfma16(al[ks].h, bh[Nt][ks].h, c);  // Wl*xh
        #pragma unroll
        for (int ks = 0; ks < 4; ++ks) c = mfma16(ah[ks].h, bl[Nt][ks].h, c);  // Wh*xl
        acc[Mt][Nt] = c;
      }
    }
    if (m < 4){
      // relu -> split -> B-frags in place (kstep of next matvec = Mt of this output)
      #pragma unroll
      for (int Mt = 0; Mt < 4; ++Mt){
        const f32x4 bv = *(const f32x4*)(pbias + (LAYER*4 + m)*64 + Mt*16 + (lg<<2));
        #pragma unroll
        for (int Nt = 0; Nt < 2; ++Nt){
          f32x4 v = acc[Mt][Nt];
          v[0]=fmaxf(v[0],0.f); v[1]=fmaxf(v[1],0.f); v[2]=fmaxf(v[2],0.f); v[3]=fmaxf(v[3],0.f);
          split4(v, bh[Nt][Mt], bl[Nt][Mt]);
          acc[Mt][Nt] = bv;                          // bias of next matvec
        }
      }
    }
  }

  // ---- store final matvec output (no relu), only j < 50 ----
  #pragma unroll
  for (int Nt = 0; Nt < 2; ++Nt){
    int node = base + Nt*16 + ll;
    if (node < N){
      float* row = xio + (size_t)node*H;
      #pragma unroll
      for (int Mt = 0; Mt < 3; ++Mt){
        int j0 = Mt*16 + (lg<<2);
        *(float2*)(row + j0)     = make_float2(acc[Mt][Nt][0], acc[Mt][Nt][1]);
        *(float2*)(row + j0 + 2) = make_float2(acc[Mt][Nt][2], acc[Mt][Nt][3]);
      }
      if (lg == 0)
        *(float2*)(row + 48) = make_float2(acc[3][Nt][0], acc[3][Nt][1]);
    }
  }

  // ---- fused BN-stats epilogue: psum/psq from registers ----
  // per (Mt,r): j fixed per lane-group; reduce over 16 ll-lanes (2 nodes each)
  {
    int slot = (int)(blockIdx.x & 63);
    #pragma unroll
    for (int Mt = 0; Mt < 4; ++Mt)
      #pragma unroll
      for (int r = 0; r < 4; ++r){
        int j = Mt*16 + lg*4 + r;
        float s = 0.f, q = 0.f;
        #pragma unroll
        for (int Nt = 0; Nt < 2; ++Nt){
          int node = base + Nt*16 + ll;
          float v = (node < N && j < H) ? acc[Mt][Nt][r] : 0.f;
          s += v; q = fmaf(v, v, q);
        }
        #pragma unroll
        for (int off = 8; off > 0; off >>= 1){ s += __shfl_xor(s, off); q += __shfl_xor(q, off); }
        if (ll == 0 && j < H){
          atomicAdd(&psum[slot*H + j], s);
          atomicAdd(&psq [slot*H + j], q);
        }
      }
  }
}

__global__ void k_finalize(float* __restrict__ psum, float* __restrict__ psq,
                           const float* __restrict__ gamma, const float* __restrict__ beta,
                           int layer, float ninv, float* __restrict__ stats){
  int j = threadIdx.x;
  if (j >= H) return;
  float s = 0.f, q = 0.f;
  #pragma unroll 8
  for (int p = 0; p < 64; ++p){ s += psum[p*H + j]; q += psq[p*H + j]; }
  float mu  = s*ninv;
  float var = q*ninv - mu*mu;
  float a = rsqrtf(var + EPSV) * gamma[layer*H + j];
  float c = beta[layer*H + j] - mu*a;
  stats[layer*100 + j]     = a;
  stats[layer*100 + H + j] = c;
  // re-zero for next layer's atomics (each (p,j) read only by this thread)
  #pragma unroll 8
  for (int p = 0; p < 64; ++p){ psum[p*H + j] = 0.f; psq[p*H + j] = 0.f; }
}

// ---- per-graph: gsum of x1 (4-wave parallel) -> BN1 affine -> tg for layer 2 ----
__global__ void k_gt1(const float* __restrict__ x, const int* __restrict__ start,
                      const float* __restrict__ stats,
                      const float* __restrict__ Ws1, const float* __restrict__ bs1,
                      float* __restrict__ tg){
  __shared__ float part[4][H];
  __shared__ float glob[H];
  int g = blockIdx.x;
  int t = threadIdx.x;                 // 256 = 4 waves
  int w = t >> 6, j = t & 63;
  int s = start[g], e = start[g+1];
  if (j < H){
    float acc = 0.f;
    for (int n = s + w; n < e; n += 4) acc += x[(size_t)n*H + j];
    part[w][j] = acc;
  }
  __syncthreads();
  if (t < H){
    int cnt = e - s; if (cnt < 1) cnt = 1;
    float m = (part[0][t] + part[1][t] + part[2][t] + part[3][t]) / (float)cnt;
    glob[t] = m*stats[t] + stats[H+t];   // a1, c1
  }
  __syncthreads();
  if (t < H){
    const float* W = Ws1 + 100*H;        // Ws1[1] rows 0..49
    float a = bs1[H + t];
    #pragma unroll 5
    for (int k = 0; k < H; ++k) a = fmaf(glob[k], W[k*H + t], a);
    tg[(size_t)g*H + t] = a;
  }
}

// ---- BN2 apply, float4 grid-stride (N*H = 50M floats = 12.5M float4 exactly) ----
__global__ void k_bnapply(float4* __restrict__ x4, const float* __restrict__ stats, int n4){
  __shared__ float a[H], c[H];
  if (threadIdx.x < H){ a[threadIdx.x] = stats[100 + threadIdx.x]; c[threadIdx.x] = stats[150 + threadIdx.x]; }
  __syncthreads();
  int idx = blockIdx.x*blockDim.x + threadIdx.x;
  int stride = gridDim.x*blockDim.x;
  for (; idx < n4; idx += stride){
    float4 v = x4[idx];
    int j0 = (idx*4) % 50;
    int j1 = j0+1; if (j1 >= 50) j1 -= 50;
    int j2 = j0+2; if (j2 >= 50) j2 -= 50;
    int j3 = j0+3; if (j3 >= 50) j3 -= 50;
    v.x = v.x*a[j0] + c[j0];
    v.y = v.y*a[j1] + c[j1];
    v.z = v.z*a[j2] + c[j2];
    v.w = v.w*a[j3] + c[j3];
    x4[idx] = v;
  }
}

extern "C" void kernel_launch(void* const* d_in, const int* in_sizes, int n_in,
                              void* d_out, int out_size, void* d_ws, size_t ws_size,
                              hipStream_t stream) {
  const float2* xy     = (const float2*)d_in[0];
  const int*    sid    = (const int*)d_in[1];
  const float*  w_init = (const float*)d_in[3];
  const float*  b_init = (const float*)d_in[4];
  const float*  Ws1    = (const float*)d_in[5];
  const float*  bs1    = (const float*)d_in[6];
  const float*  Ws     = (const float*)d_in[7];
  const float*  bs     = (const float*)d_in[8];
  const float*  gamma  = (const float*)d_in[9];
  const float*  beta   = (const float*)d_in[10];
  float* out = (float*)d_out;
  int N = in_sizes[0] / 2;
  const int G = GN;

  char* ws = (char*)d_ws;
  int*   start = (int*)ws;                      // 40,004 B          [0 .. 40064)
  float* tg    = (float*)(ws + 40064);          // 50G floats (2 MB) [.. 2040064)
  float* psum  = (float*)(ws + 2040064);        // 64*50 floats      [.. 2052864)
  float* psq   = (float*)(ws + 2052864);        // 64*50 floats      [.. 2065664)
  float* stats = (float*)(ws + 2065664);        // 200 floats        [.. 2066464)
  uint4* frag  = (uint4*)(ws + 2066560);        // 163,840 B         [.. 2230400)
  float* pbias = (float*)(ws + 2230400);        // 2,048 B

  int nb = (N + 127)/128;
  int n4 = (N*H)/4;

  k_pre<<<107, 256, 0, stream>>>(Ws1, Ws, bs, sid, N, frag, pbias, start, psum);
  k_ginit0<<<G, 64, 0, stream>>>(xy, start, w_init, b_init, Ws1, bs1, tg);
  k_layer<0><<<nb, 256, 0, stream>>>(xy, sid, tg, frag, pbias, w_init, b_init, stats, psum, psq, out, N);
  k_finalize<<<1, 64, 0, stream>>>(psum, psq, gamma, beta, 0, 1.0f/(float)N, stats);
  k_gt1<<<G, 256, 0, stream>>>(out, start, stats, Ws1, bs1, tg);
  k_layer<1><<<nb, 256, 0, stream>>>(xy, sid, tg, frag, pbias, w_init, b_init, stats, psum, psq, out, N);
  k_finalize<<<1, 64, 0, stream>>>(psum, psq, gamma, beta, 1, 1.0f/(float)N, stats);
  k_bnapply<<<4096, 256, 0, stream>>>((float4*)out, stats, n4);
}

// Round 8
// 713.906 us; speedup vs baseline: 2.6610x; 1.5277x over previous
//
#include <hip/hip_runtime.h>

// DeepSet: N=1M nodes, G=10k graphs (sorted segment ids), HIDDEN=50, 2 layers.
// v7: k_layer moves to the gfx950-native v_mfma_f32_16x16x32_f16 (K=32) --
// half the MFMA instructions of the legacy 16x16x16 chain. Chaining stays
// register-resident via a k-index permutation applied consistently to BOTH
// operands: pi(ks,lg,e) = (2ks+(e>>2))*16 + lg*4 + (e&3). W side is baked in
// k_pre (free); x side makes the next B-frag a register CONCAT of the split
// output (no shuffles, no LDS). launch_bounds(256,4): arch-VGPR budget ~64
// (gfx950 splits unified file ~evenly arch/acc; bounds 6/8 spilled).
//   k_pre      : W^T MFMA A-fragments (f16 hi/lo, pi-permuted k) + padded
//                biases + start[] binary search + psum/psq zeroing
//   k_ginit0   : per-graph xy mean + tg = glob@Ws1[L0][:50]+bs1[0]
//   k_layer<L> : register-resident K=32 MFMA matvec chain (fp32 emu:
//                xh@Wh + xl@Wh + xh@Wl); fused BN sum/sumsq epilogue
//   k_finalize : a,c from psum/psq; re-zeros psum/psq
//   k_gt1      : per-graph sum of x1 -> BN1 affine -> tg for layer 2
//   k_bnapply  : out = out*a2 + c2 (float4 grid-stride)

#define GN 10000
#define H 50
#define EPSV 1e-5f

typedef __attribute__((ext_vector_type(4))) float f32x4;
typedef __attribute__((ext_vector_type(2))) __fp16 fp16x2;
typedef __attribute__((ext_vector_type(4))) _Float16 half4_t;
typedef __attribute__((ext_vector_type(8))) _Float16 half8_t;

union H4 { half4_t h; uint2 u; };
union H8 { half8_t h; uint4 u; };

static __device__ __forceinline__ f32x4 mfma32(half8_t a, half8_t b, f32x4 c){
#if __has_builtin(__builtin_amdgcn_mfma_f32_16x16x32_f16)
  return __builtin_amdgcn_mfma_f32_16x16x32_f16(a, b, c, 0, 0, 0);
#else
  asm volatile("v_mfma_f32_16x16x32_f16 %0, %1, %2, %0" : "+v"(c) : "v"(a), "v"(b));
  return c;
#endif
}

// split fp32x4 into f16 hi plane + f16 residual plane
static __device__ __forceinline__ void split4(f32x4 v, H4& hh, H4& hl){
  fp16x2 a = __builtin_amdgcn_cvt_pkrtz(v[0], v[1]);
  fp16x2 b = __builtin_amdgcn_cvt_pkrtz(v[2], v[3]);
  hh.u.x = __builtin_bit_cast(unsigned int, a);
  hh.u.y = __builtin_bit_cast(unsigned int, b);
  float r0 = v[0] - (float)a[0];
  float r1 = v[1] - (float)a[1];
  float r2 = v[2] - (float)b[0];
  float r3 = v[3] - (float)b[1];
  fp16x2 c = __builtin_amdgcn_cvt_pkrtz(r0, r1);
  fp16x2 d = __builtin_amdgcn_cvt_pkrtz(r2, r3);
  hl.u.x = __builtin_bit_cast(unsigned int, c);
  hl.u.y = __builtin_bit_cast(unsigned int, d);
}

// ---- fused prepass: W fragments + padded biases + start[] + psum/psq zero ----
// frag uint4 index: (((L*5+m)*4 + Mt)*2 + ks)*2 + pl, 64 lanes each.
// A operand (16x16x32): row j_out = Mt*16 + (lane&15); slot e of instr ks holds
// logical k = (2*ks + (e>>2))*16 + (lane>>4)*4 + (e&3)   [pi permutation]
__global__ void k_pre(const float* __restrict__ Ws1, const float* __restrict__ Ws,
                      const float* __restrict__ bs, const int* __restrict__ sid, int N,
                      uint4* __restrict__ frag, float* __restrict__ pbias,
                      int* __restrict__ start, float* __restrict__ pzero){
  int t = blockIdx.x*blockDim.x + threadIdx.x;
  if (t < 10240){
    int lane = t & 63;
    int pl   = (t>>6) & 1;
    int ks   = (t>>7) & 1;
    int Mt   = (t>>8) & 3;
    int rest = t >> 10;                 // 0..9 = L*5 + m
    int m = rest % 5, L = rest / 5;
    const float* W = (m == 0) ? (Ws1 + L*100*H + H*H) : (Ws + (L*4 + (m-1))*H*H);
    int jo = Mt*16 + (lane & 15);
    int lg = lane >> 4;
    f32x4 v0, v1;
    #pragma unroll
    for (int e = 0; e < 4; ++e){
      int k0 = (2*ks)*16   + lg*4 + e;
      int k1 = (2*ks+1)*16 + lg*4 + e;
      v0[e] = (k0 < H && jo < H) ? W[k0*H + jo] : 0.f;   // zero-pad kills 50->64 pad
      v1[e] = (k1 < H && jo < H) ? W[k1*H + jo] : 0.f;
    }
    H4 h0, l0, h1, l1;
    split4(v0, h0, l0);
    split4(v1, h1, l1);
    frag[t] = pl ? make_uint4(l0.u.x, l0.u.y, l1.u.x, l1.u.y)
                 : make_uint4(h0.u.x, h0.u.y, h1.u.x, h1.u.y);
  } else if (t < 10752){
    int i = t - 10240;                  // (L*4+mi)*64 + j, 512 entries
    int j = i & 63;
    int row = i >> 6;
    pbias[i] = (j < H) ? bs[row*H + j] : 0.f;
  } else if (t < 20753){
    int g = t - 10752;                  // 0..10000
    int lo = 0, hi = N;
    while (lo < hi){ int mid = (lo+hi)>>1; if (sid[mid] < g) lo = mid+1; else hi = mid; }
    start[g] = lo;
  } else if (t >= 20800 && t < 27200){
    pzero[t - 20800] = 0.f;             // psum+psq contiguous, 6400 floats
  }
}

// ---- per-graph: xy mean + tg for layer 0 ----
__global__ void k_ginit0(const float2* __restrict__ xy, const int* __restrict__ start,
                         const float* __restrict__ w_init, const float* __restrict__ b_init,
                         const float* __restrict__ Ws1, const float* __restrict__ bs1,
                         float* __restrict__ tg){
  __shared__ float glob[H];
  int g = blockIdx.x; int l = threadIdx.x;     // 64 threads = 1 wave
  int s = start[g], e = start[g+1];
  float sx = 0.f, sy = 0.f;
  for (int n = s + l; n < e; n += 64){ float2 v = xy[n]; sx += v.x; sy += v.y; }
  #pragma unroll
  for (int off = 32; off > 0; off >>= 1){ sx += __shfl_xor(sx, off); sy += __shfl_xor(sy, off); }
  int cnt = e - s; if (cnt < 1) cnt = 1;
  float inv = 1.f/(float)cnt;
  if (l < H) glob[l] = b_init[l] + sx*inv*w_init[l] + sy*inv*w_init[H+l];
  __syncthreads();
  if (l < H){
    float a = bs1[l];
    #pragma unroll 5
    for (int k = 0; k < H; ++k) a = fmaf(glob[k], Ws1[k*H + l], a);
    tg[(size_t)g*H + l] = a;
  }
}

template<int LAYER>
__global__ __launch_bounds__(256, 4)
void k_layer(const float2* __restrict__ xy, const int* __restrict__ sid,
             const float* __restrict__ tg, const uint4* __restrict__ frag,
             const float* __restrict__ pbias,
             const float* __restrict__ w_init, const float* __restrict__ b_init,
             const float* __restrict__ stats,
             float* __restrict__ psum, float* __restrict__ psq,
             float* __restrict__ xio, int N)
{
  const int tid = threadIdx.x;
  const int wv = tid >> 6, l = tid & 63, lg = l >> 4, ll = l & 15;
  const int base = blockIdx.x*128 + wv*32;     // 32 nodes per wave, 4 waves/block

  // ---- B-fragments for matvec 0 (pi-permuted k: slot(ks,e) = logical
  //      k = (2ks+(e>>2))*16 + lg*4 + (e&3); col n = node = Nt*16+ll) ----
  H8 bh[2][2], bl[2][2];
  #pragma unroll
  for (int Nt = 0; Nt < 2; ++Nt){
    int node = base + Nt*16 + ll;
    int nc = node < N ? node : N-1;
    H4 sh[4], sl[4];
    float2 p;
    if (LAYER == 0) p = xy[nc];
    #pragma unroll
    for (int Mt2 = 0; Mt2 < 4; ++Mt2){
      float xv[4];
      if (LAYER == 0){
        #pragma unroll
        for (int e = 0; e < 4; ++e){
          int k = Mt2*16 + lg*4 + e; int kc = k < H ? k : H-1;   // pad -> finite garbage, W-zeros kill it
          xv[e] = b_init[kc] + p.x*w_init[kc] + p.y*w_init[H+kc];
        }
      } else {
        int k0 = Mt2*16 + lg*4;
        size_t f0 = (size_t)nc*H + k0;
        size_t fm = (size_t)N*H - 2;
        float2 u0 = *(const float2*)(xio + (f0     < fm ? f0     : fm));
        float2 u1 = *(const float2*)(xio + (f0 + 2 < fm ? f0 + 2 : fm));
        float vv[4] = {u0.x, u0.y, u1.x, u1.y};
        #pragma unroll
        for (int e = 0; e < 4; ++e){
          int kc = (k0+e) < H ? (k0+e) : H-1;
          xv[e] = vv[e]*stats[kc] + stats[H+kc];                 // BN1 affine on the way in
        }
      }
      f32x4 v; v[0]=xv[0]; v[1]=xv[1]; v[2]=xv[2]; v[3]=xv[3];
      split4(v, sh[Mt2], sl[Mt2]);
    }
    #pragma unroll
    for (int ks = 0; ks < 2; ++ks){
      bh[Nt][ks].u = make_uint4(sh[2*ks].u.x, sh[2*ks].u.y, sh[2*ks+1].u.x, sh[2*ks+1].u.y);
      bl[Nt][ks].u = make_uint4(sl[2*ks].u.x, sl[2*ks].u.y, sl[2*ks+1].u.x, sl[2*ks+1].u.y);
    }
  }

  // ---- acc init = tg[g] (per-graph glob part + bs1, fp32-exact) ----
  // D layout: col n = node = Nt*16+ll, row j = Mt*16 + lg*4 + r
  f32x4 acc[4][2];
  {
    int n0 = base + ll;       n0 = n0 < N ? n0 : N-1;
    int n1 = base + 16 + ll;  n1 = n1 < N ? n1 : N-1;
    const float* t0 = tg + (size_t)sid[n0]*H;
    const float* t1 = tg + (size_t)sid[n1]*H;
    #pragma unroll
    for (int Mt = 0; Mt < 4; ++Mt)
      #pragma unroll
      for (int r = 0; r < 4; ++r){
        int j = Mt*16 + lg*4 + r; int jc = j < H ? j : H-1;
        acc[Mt][0][r] = t0[jc];
        acc[Mt][1][r] = t1[jc];
      }
  }

  // ---- 5 chained matvecs; K=32 MFMA; next B-frags = register concat ----
  #pragma unroll
  for (int m = 0; m < 5; ++m){
    const uint4* fp = frag + (LAYER*5 + m)*1024;
    #pragma unroll
    for (int Mt = 0; Mt < 4; ++Mt){
      H8 ah[2], al[2];
      #pragma unroll
      for (int ks = 0; ks < 2; ++ks){
        ah[ks].u = fp[((Mt*2 + ks)*2 + 0)*64 + l];   // hi plane
        al[ks].u = fp[((Mt*2 + ks)*2 + 1)*64 + l];   // lo plane
      }
      #pragma unroll
      for (int Nt = 0; Nt < 2; ++Nt){
        f32x4 c = acc[Mt][Nt];
        c = mfma32(ah[0].h, bh[Nt][0].h, c);   // Wh*xh
        c = mfma32(ah[1].h, bh[Nt][1].h, c);
        c = mfma32(al[0].h, bh[Nt][0].h, c);   // Wl*xh
        c = mfma32(al[1].h, bh[Nt][1].h, c);
        c = mfma32(ah[0].h, bl[Nt][0].h, c);   // Wh*xl
        c = mfma32(ah[1].h, bl[Nt][1].h, c);
        acc[Mt][Nt] = c;
      }
    }
    if (m < 4){
      // relu -> split -> concat into next B-frags; reset acc to next bias
      #pragma unroll
      for (int Nt = 0; Nt < 2; ++Nt){
        H4 sh[4], sl[4];
        #pragma unroll
        for (int Mt = 0; Mt < 4; ++Mt){
          const f32x4 bv = *(const f32x4*)(pbias + (LAYER*4 + m)*64 + Mt*16 + (lg<<2));
          f32x4 v = acc[Mt][Nt];
          v[0]=fmaxf(v[0],0.f); v[1]=fmaxf(v[1],0.f); v[2]=fmaxf(v[2],0.f); v[3]=fmaxf(v[3],0.f);
          split4(v, sh[Mt], sl[Mt]);
          acc[Mt][Nt] = bv;
        }
        #pragma unroll
        for (int ks = 0; ks < 2; ++ks){
          bh[Nt][ks].u = make_uint4(sh[2*ks].u.x, sh[2*ks].u.y, sh[2*ks+1].u.x, sh[2*ks+1].u.y);
          bl[Nt][ks].u = make_uint4(sl[2*ks].u.x, sl[2*ks].u.y, sl[2*ks+1].u.x, sl[2*ks+1].u.y);
        }
      }
    }
  }

  // ---- store final matvec output (no relu), only j < 50 ----
  #pragma unroll
  for (int Nt = 0; Nt < 2; ++Nt){
    int node = base + Nt*16 + ll;
    if (node < N){
      float* row = xio + (size_t)node*H;
      #pragma unroll
      for (int Mt = 0; Mt < 3; ++Mt){
        int j0 = Mt*16 + (lg<<2);
        *(float2*)(row + j0)     = make_float2(acc[Mt][Nt][0], acc[Mt][Nt][1]);
        *(float2*)(row + j0 + 2) = make_float2(acc[Mt][Nt][2], acc[Mt][Nt][3]);
      }
      if (lg == 0)
        *(float2*)(row + 48) = make_float2(acc[3][Nt][0], acc[3][Nt][1]);
    }
  }

  // ---- fused BN-stats epilogue: psum/psq from registers ----
  // per (Mt,r): j fixed per lane-group; reduce over 16 ll-lanes (2 nodes each)
  {
    int slot = (int)(blockIdx.x & 63);
    #pragma unroll
    for (int Mt = 0; Mt < 4; ++Mt)
      #pragma unroll
      for (int r = 0; r < 4; ++r){
        int j = Mt*16 + lg*4 + r;
        float s = 0.f, q = 0.f;
        #pragma unroll
        for (int Nt = 0; Nt < 2; ++Nt){
          int node = base + Nt*16 + ll;
          float v = (node < N && j < H) ? acc[Mt][Nt][r] : 0.f;
          s += v; q = fmaf(v, v, q);
        }
        #pragma unroll
        for (int off = 8; off > 0; off >>= 1){ s += __shfl_xor(s, off); q += __shfl_xor(q, off); }
        if (ll == 0 && j < H){
          atomicAdd(&psum[slot*H + j], s);
          atomicAdd(&psq [slot*H + j], q);
        }
      }
  }
}

__global__ void k_finalize(float* __restrict__ psum, float* __restrict__ psq,
                           const float* __restrict__ gamma, const float* __restrict__ beta,
                           int layer, float ninv, float* __restrict__ stats){
  int j = threadIdx.x;
  if (j >= H) return;
  float s = 0.f, q = 0.f;
  #pragma unroll 8
  for (int p = 0; p < 64; ++p){ s += psum[p*H + j]; q += psq[p*H + j]; }
  float mu  = s*ninv;
  float var = q*ninv - mu*mu;
  float a = rsqrtf(var + EPSV) * gamma[layer*H + j];
  float c = beta[layer*H + j] - mu*a;
  stats[layer*100 + j]     = a;
  stats[layer*100 + H + j] = c;
  // re-zero for next layer's atomics (each (p,j) read only by this thread)
  #pragma unroll 8
  for (int p = 0; p < 64; ++p){ psum[p*H + j] = 0.f; psq[p*H + j] = 0.f; }
}

// ---- per-graph: gsum of x1 (4-wave parallel) -> BN1 affine -> tg for layer 2 ----
__global__ void k_gt1(const float* __restrict__ x, const int* __restrict__ start,
                      const float* __restrict__ stats,
                      const float* __restrict__ Ws1, const float* __restrict__ bs1,
                      float* __restrict__ tg){
  __shared__ float part[4][H];
  __shared__ float glob[H];
  int g = blockIdx.x;
  int t = threadIdx.x;                 // 256 = 4 waves
  int w = t >> 6, j = t & 63;
  int s = start[g], e = start[g+1];
  if (j < H){
    float acc = 0.f;
    for (int n = s + w; n < e; n += 4) acc += x[(size_t)n*H + j];
    part[w][j] = acc;
  }
  __syncthreads();
  if (t < H){
    int cnt = e - s; if (cnt < 1) cnt = 1;
    float m = (part[0][t] + part[1][t] + part[2][t] + part[3][t]) / (float)cnt;
    glob[t] = m*stats[t] + stats[H+t];   // a1, c1
  }
  __syncthreads();
  if (t < H){
    const float* W = Ws1 + 100*H;        // Ws1[1] rows 0..49
    float a = bs1[H + t];
    #pragma unroll 5
    for (int k = 0; k < H; ++k) a = fmaf(glob[k], W[k*H + t], a);
    tg[(size_t)g*H + t] = a;
  }
}

// ---- BN2 apply, float4 grid-stride (N*H = 50M floats = 12.5M float4 exactly) ----
__global__ void k_bnapply(float4* __restrict__ x4, const float* __restrict__ stats, int n4){
  __shared__ float a[H], c[H];
  if (threadIdx.x < H){ a[threadIdx.x] = stats[100 + threadIdx.x]; c[threadIdx.x] = stats[150 + threadIdx.x]; }
  __syncthreads();
  int idx = blockIdx.x*blockDim.x + threadIdx.x;
  int stride = gridDim.x*blockDim.x;
  for (; idx < n4; idx += stride){
    float4 v = x4[idx];
    int j0 = (idx*4) % 50;
    int j1 = j0+1; if (j1 >= 50) j1 -= 50;
    int j2 = j0+2; if (j2 >= 50) j2 -= 50;
    int j3 = j0+3; if (j3 >= 50) j3 -= 50;
    v.x = v.x*a[j0] + c[j0];
    v.y = v.y*a[j1] + c[j1];
    v.z = v.z*a[j2] + c[j2];
    v.w = v.w*a[j3] + c[j3];
    x4[idx] = v;
  }
}

extern "C" void kernel_launch(void* const* d_in, const int* in_sizes, int n_in,
                              void* d_out, int out_size, void* d_ws, size_t ws_size,
                              hipStream_t stream) {
  const float2* xy     = (const float2*)d_in[0];
  const int*    sid    = (const int*)d_in[1];
  const float*  w_init = (const float*)d_in[3];
  const float*  b_init = (const float*)d_in[4];
  const float*  Ws1    = (const float*)d_in[5];
  const float*  bs1    = (const float*)d_in[6];
  const float*  Ws     = (const float*)d_in[7];
  const float*  bs     = (const float*)d_in[8];
  const float*  gamma  = (const float*)d_in[9];
  const float*  beta   = (const float*)d_in[10];
  float* out = (float*)d_out;
  int N = in_sizes[0] / 2;
  const int G = GN;

  char* ws = (char*)d_ws;
  int*   start = (int*)ws;                      // 40,004 B          [0 .. 40064)
  float* tg    = (float*)(ws + 40064);          // 50G floats (2 MB) [.. 2040064)
  float* psum  = (float*)(ws + 2040064);        // 64*50 floats      [.. 2052864)
  float* psq   = (float*)(ws + 2052864);        // 64*50 floats      [.. 2065664)
  float* stats = (float*)(ws + 2065664);        // 200 floats        [.. 2066464)
  uint4* frag  = (uint4*)(ws + 2066560);        // 163,840 B         [.. 2230400)
  float* pbias = (float*)(ws + 2230400);        // 2,048 B

  int nb = (N + 127)/128;
  int n4 = (N*H)/4;

  k_pre<<<107, 256, 0, stream>>>(Ws1, Ws, bs, sid, N, frag, pbias, start, psum);
  k_ginit0<<<G, 64, 0, stream>>>(xy, start, w_init, b_init, Ws1, bs1, tg);
  k_layer<0><<<nb, 256, 0, stream>>>(xy, sid, tg, frag, pbias, w_init, b_init, stats, psum, psq, out, N);
  k_finalize<<<1, 64, 0, stream>>>(psum, psq, gamma, beta, 0, 1.0f/(float)N, stats);
  k_gt1<<<G, 256, 0, stream>>>(out, start, stats, Ws1, bs1, tg);
  k_layer<1><<<nb, 256, 0, stream>>>(xy, sid, tg, frag, pbias, w_init, b_init, stats, psum, psq, out, N);
  k_finalize<<<1, 64, 0, stream>>>(psum, psq, gamma, beta, 1, 1.0f/(float)N, stats);
  k_bnapply<<<4096, 256, 0, stream>>>((float4*)out, stats, n4);
}